// Round 1
// baseline (823.486 us; speedup 1.0000x reference)
//
#include <hip/hip_runtime.h>
#include <math.h>

#define L_ 8
#define D_ 128
#define B_ 8192
#define P_ 28
#define ALPHA_ 0.1f

typedef __attribute__((ext_vector_type(8))) short bf16x8;
typedef __attribute__((ext_vector_type(4))) float f32x4;
union BF8 { int4 i; bf16x8 h; short s[8]; };

__device__ __forceinline__ short f2bf(float f) {
    unsigned u = __float_as_uint(f);
    unsigned r = (u + 0x7fffu + ((u >> 16) & 1u)) >> 16;   // RNE
    return (short)(r & 0xffffu);
}
__device__ __forceinline__ unsigned rne2(float a, float b) {
    unsigned ua = __float_as_uint(a); ua += 0x7fffu + ((ua >> 16) & 1u);
    unsigned ub = __float_as_uint(b); ub += 0x7fffu + ((ub >> 16) & 1u);
    return __builtin_amdgcn_perm(ub, ua, 0x07060302);      // {b_hi16, a_hi16} -> mem order a,b
}
__device__ __forceinline__ unsigned cvt_pk_bf16(float lo, float hi) {
    unsigned r;
    asm("v_cvt_pk_bf16_f32 %0, %1, %2" : "=v"(r) : "v"(lo), "v"(hi));
    return r;
}
__device__ __forceinline__ float fast_tanh(float x) {
    float e = exp2f(x * 2.885390081777927f);               // e^{2x}
    return 1.f - 2.f * __builtin_amdgcn_rcpf(e + 1.f);
}

typedef const unsigned int __attribute__((address_space(1)))* gas_t;
typedef unsigned int __attribute__((address_space(3)))* las_t;

// ---------------------------------------------------------------------------
// W transpose -> bf16, fragment-blocked AND pre-swizzled so that a LINEAR
// global_load_lds of one 8KB kb-slice lands in LDS with the XOR-swizzle
// byte ^= ((row&7)<<4) already applied (row = output-neuron index within a
// 16-wide ct tile). Slice layout (bytes): ct*1024 + mrow*64 + kk*2, XORed.
// ---------------------------------------------------------------------------
__global__ void transpose_w(const float* __restrict__ W1, const float* __restrict__ W2,
                            short* __restrict__ T1, short* __restrict__ T2) {
    const float* W = blockIdx.y ? W2 : W1;
    short* T = blockIdx.y ? T2 : T1;
    const int p = blockIdx.x >> 3, kb = blockIdx.x & 7;
    __shared__ float tile[32][260];
    const int tid = threadIdx.x;
    for (int s = tid; s < 8192; s += 256) {
        int kk = s >> 8, n = s & 255;
        tile[kk][n] = W[((size_t)p * 256 + kb * 32 + kk) * 256 + n];
    }
    __syncthreads();
    const int n = tid;
    const int ch = n >> 7, ct = (n >> 4) & 7, mm = n & 15;
    const size_t sb = (((size_t)p * 2 + ch) * 64 + kb * 8) * 512;   // kb-slice base (shorts)
    short tmp[32];
#pragma unroll
    for (int kk = 0; kk < 32; ++kk) tmp[kk] = f2bf(tile[kk][n]);
#pragma unroll
    for (int c4 = 0; c4 < 4; ++c4) {
        BF8 u;
#pragma unroll
        for (int e = 0; e < 8; ++e) u.s[e] = tmp[c4 * 8 + e];
        const int byt = (ct * 1024 + mm * 64 + c4 * 16) ^ ((mm & 7) << 4);
        *(int4*)&T[sb + (byt >> 1)] = u.i;
    }
}

// ---------------------------------------------------------------------------
// S (f32) -> bf16 B-fragment layout, computed ONCE (was re-converted 14x in
// the old gemm1). Per 16-row group rg: 2048 shorts, elem(row,k) at
// (k/8 *16 + row%16)*8 + k%8  -> lane (m=row,q) reads 16B contiguous.
// ---------------------------------------------------------------------------
__global__ void prep_s16(const float* __restrict__ S, short* __restrict__ S16) {
    __shared__ __align__(16) short ls[8192];            // 16 KB bounce, bank-swizzled
    const int t = threadIdx.x;
    const size_t base = (size_t)blockIdx.x * 8192;      // 64 rows x 128
#pragma unroll
    for (int rr = 0; rr < 8; ++rr) {
        const int idx = rr * 1024 + t * 4;
        const float4 v = *(const float4*)&S[base + idx];
        const int row = idx >> 7, col = idx & 127;
        const int rgl = row >> 4, mr = row & 15, kq = col >> 3, c4 = (col >> 2) & 1;
        const unsigned w0 = rne2(v.x, v.y), w1 = rne2(v.z, v.w);
        const int byt = (rgl * 4096 + kq * 256 + mr * 16 + c4 * 8) ^ ((kq & 7) << 4);
        *(uint2*)((char*)ls + byt) = (uint2){w0, w1};
    }
    __syncthreads();
#pragma unroll
    for (int r = 0; r < 4; ++r) {
        const int un = r * 256 + t;                      // 16-B unit
        const int kq = (un >> 4) & 15;
        const int byt = (un * 16) ^ ((kq & 7) << 4);
        *(int4*)&S16[base + (size_t)un * 8] = *(const int4*)((const char*)ls + byt);
    }
}

// stage source for flat stage index s (24 stages of 8KB per partner-iter):
//   0-7  : W1[p*2+0][kb 0..7]      (G1 half hh=0)
//   8-11 : W2[p*2+side][kc 0..3]   (G2 partial, K-chunks of hh=0)
//   12-19: W1[p*2+1][kb 0..7]      (G1 half hh=1)
//   20-23: W2[p*2+side][kc 4..7]
__device__ __forceinline__ const short* stage_src(int s, int k,
                                                  const short* T1, const short* T2) {
    const int it = s / 24, sub = s - it * 24;
    const int mm = it + (it >= k ? 1 : 0);
    const int i = k < mm ? k : mm;
    const int j = k < mm ? mm : k;
    const int p = i * 7 - ((i * (i - 1)) >> 1) + (j - i - 1);
    const int side = (k == i) ? 0 : 1;
    if (sub < 8)  return T1 + ((size_t)(p * 2) << 15)        + ((size_t)sub << 12);
    if (sub < 12) return T2 + ((size_t)(p * 2 + side) << 15) + ((size_t)(sub - 8) << 12);
    if (sub < 20) return T1 + ((size_t)(p * 2 + 1) << 15)    + ((size_t)(sub - 12) << 12);
    return T2 + ((size_t)(p * 2 + side) << 15) + ((size_t)(sub - 16) << 12);
}

__device__ __forceinline__ void stage_step(int s, int k, const short* T1, const short* T2,
                                           short (*Wl)[4096], int w, int lane) {
    if (s >= 168) return;
    const short* src = stage_src(s, k, T1, T2);
    short* dst = Wl[s & 1];
#pragma unroll
    for (int r = 0; r < 2; ++r) {
        const int u0 = r * 256 + w * 64;
        __builtin_amdgcn_global_load_lds((gas_t)(const void*)(src + (size_t)(u0 + lane) * 8),
                                         (las_t)(void*)(dst + u0 * 8), 16, 0, 0);
    }
}

// ---------------------------------------------------------------------------
// Fused per-layer kernel. Block = (layer k, 128 rows). For each of k's 7
// partners in global pair order: G1 full (swapped operands: A=W1^T frag,
// B=S frag -> C[row=hidden, col=batch]), tanh -> bf16 H in LDS (swizzled),
// G2 restricted to layer k's 128 output cols, u += alpha*(st*(bell+b2)-u)
// in registers. ENT / H global buffers and the finalize kernel are gone.
// ---------------------------------------------------------------------------
__launch_bounds__(256, 2)
__global__ void fused(const float* __restrict__ S, const float* __restrict__ ES,
                      const float* __restrict__ b1, const float* __restrict__ b2,
                      const short* __restrict__ S16, const short* __restrict__ T1,
                      const short* __restrict__ T2, float* __restrict__ OUT) {
    __shared__ __align__(16) short Wl[2][4096];   // 2 x 8 KB W staging (dbuf)
    __shared__ __align__(16) short Hs[16384];     // 32 KB: h half-tile [row 128][hid 128]
    const int k = blockIdx.y, rb = blockIdx.x;
    const int tid = threadIdx.x, lane = tid & 63, w = tid >> 6;
    const int m = lane & 15, q = lane >> 4;
    const int swzm = (m & 7) << 4;

    // u init: wave w owns d-slice [w*32, w*32+32), all 128 rows
    const size_t srow = (size_t)k * B_ + rb * 128;
    f32x4 u[2][8];
#pragma unroll
    for (int at = 0; at < 2; ++at)
#pragma unroll
        for (int nt = 0; nt < 8; ++nt)
            u[at][nt] = *(const f32x4*)&S[(srow + nt * 16 + m) * D_ + w * 32 + at * 16 + q * 4];

    stage_step(0, k, T1, T2, Wl, w, lane);
    __syncthreads();                               // stage 0 resident

    for (int it = 0; it < 7; ++it) {
        const int mp = it + (it >= k ? 1 : 0);     // partner (ascending = global pair order)
        const int li = k < mp ? k : mp;
        const int lj = k < mp ? mp : k;
        const int p  = li * 7 - ((li * (li - 1)) >> 1) + (lj - li - 1);
        const int side = (k == li) ? 0 : 1;
        const float es = ES[li * L_ + lj];
        const float st = 1.f / (1.f + expf(-es));

        f32x4 acc2[2][8];
#pragma unroll
        for (int at = 0; at < 2; ++at)
#pragma unroll
            for (int nt = 0; nt < 8; ++nt) acc2[at][nt] = (f32x4){0.f, 0.f, 0.f, 0.f};

        for (int hh = 0; hh < 2; ++hh) {
            const int sb = it * 24 + hh * 12;
            // ---- G1: hidden half hh, wave owns 32 hidden (ct = w*2+at) ----
            f32x4 acc1[2][8];
#pragma unroll
            for (int at = 0; at < 2; ++at) {
                const f32x4 bv = *(const f32x4*)&b1[p * 256 + hh * 128 + w * 32 + at * 16 + q * 4];
#pragma unroll
                for (int nt = 0; nt < 8; ++nt) acc1[at][nt] = bv;
            }
#pragma unroll
            for (int kb = 0; kb < 8; ++kb) {
                const int s = sb + kb;
                stage_step(s + 1, k, T1, T2, Wl, w, lane);
                const int lb = (kb < 4) ? li : lj;          // comb = [s_i | s_j]
                const int kbl = kb & 3;
                const char* wb = (const char*)Wl[s & 1];
                const bf16x8 A0 = *(const bf16x8*)(wb + (((w * 2 + 0) * 1024 + m * 64 + q * 16) ^ swzm));
                const bf16x8 A1 = *(const bf16x8*)(wb + (((w * 2 + 1) * 1024 + m * 64 + q * 16) ^ swzm));
                const short* sp = S16 + ((size_t)lb * 512 + rb * 8) * 2048
                                      + ((kbl * 4 + q) * 16 + m) * 8;
#pragma unroll
                for (int nt = 0; nt < 8; ++nt) {
                    const bf16x8 Bf = *(const bf16x8*)(sp + nt * 2048);
                    acc1[0][nt] = __builtin_amdgcn_mfma_f32_16x16x32_bf16(A0, Bf, acc1[0][nt], 0, 0, 0);
                    acc1[1][nt] = __builtin_amdgcn_mfma_f32_16x16x32_bf16(A1, Bf, acc1[1][nt], 0, 0, 0);
                }
                __syncthreads();
            }
            // ---- tanh -> bf16 -> swizzled LDS H (per lane: 4 consecutive hidden, 1 row) ----
#pragma unroll
            for (int at = 0; at < 2; ++at)
#pragma unroll
                for (int nt = 0; nt < 8; ++nt) {
                    const float v0 = fast_tanh(acc1[at][nt][0]);
                    const float v1 = fast_tanh(acc1[at][nt][1]);
                    const float v2 = fast_tanh(acc1[at][nt][2]);
                    const float v3 = fast_tanh(acc1[at][nt][3]);
                    const unsigned p0 = cvt_pk_bf16(v0, v1);
                    const unsigned p1 = cvt_pk_bf16(v2, v3);
                    const int row = nt * 16 + m;
                    const int hb = (w * 32 + at * 16 + q * 4) * 2;
                    *(uint2*)((char*)Hs + ((row * 256 + hb) ^ swzm)) = (uint2){p0, p1};
                }
            __syncthreads();                       // H half visible to all waves
            // ---- G2 partial: K-chunks of this hidden half, output = side's 128 cols ----
#pragma unroll
            for (int kc = 0; kc < 4; ++kc) {
                const int s = sb + 8 + kc;
                stage_step(s + 1, k, T1, T2, Wl, w, lane);
                const char* wb = (const char*)Wl[s & 1];
                const bf16x8 A0 = *(const bf16x8*)(wb + (((w * 2 + 0) * 1024 + m * 64 + q * 16) ^ swzm));
                const bf16x8 A1 = *(const bf16x8*)(wb + (((w * 2 + 1) * 1024 + m * 64 + q * 16) ^ swzm));
                const int cb = kc * 64 + q * 16;
#pragma unroll
                for (int nt = 0; nt < 8; ++nt) {
                    const int row = nt * 16 + m;
                    const bf16x8 Hf = *(const bf16x8*)((const char*)Hs + ((row * 256 + cb) ^ swzm));
                    acc2[0][nt] = __builtin_amdgcn_mfma_f32_16x16x32_bf16(A0, Hf, acc2[0][nt], 0, 0, 0);
                    acc2[1][nt] = __builtin_amdgcn_mfma_f32_16x16x32_bf16(A1, Hf, acc2[1][nt], 0, 0, 0);
                }
                __syncthreads();
            }
        }
        // ---- sequential propagation step (exact reference order, f32) ----
#pragma unroll
        for (int at = 0; at < 2; ++at) {
            const f32x4 bv = *(const f32x4*)&b2[p * 256 + side * 128 + w * 32 + at * 16 + q * 4];
#pragma unroll
            for (int nt = 0; nt < 8; ++nt)
#pragma unroll
                for (int r = 0; r < 4; ++r) {
                    const float e = st * (acc2[at][nt][r] + bv[r]);
                    u[at][nt][r] += ALPHA_ * (e - u[at][nt][r]);
                }
        }
    }

#pragma unroll
    for (int nt = 0; nt < 8; ++nt)
#pragma unroll
        for (int at = 0; at < 2; ++at)
            *(f32x4*)&OUT[(srow + nt * 16 + m) * D_ + w * 32 + at * 16 + q * 4] = u[at][nt];
}

// measures analytically constant (lam1 == 1 after normalize):
// (127+127-255)*1e-12*(-ln 1e-12) = -2.7631021115928547e-11
__global__ void fill_meas(float* __restrict__ M) {
    int t = blockIdx.x * 256 + threadIdx.x;
    if (t < P_ * B_) M[t] = -2.7631021115928547e-11f;
}

extern "C" void kernel_launch(void* const* d_in, const int* in_sizes, int n_in,
                              void* d_out, int out_size, void* d_ws, size_t ws_size,
                              hipStream_t stream) {
    const float* S  = (const float*)d_in[0];
    const float* ES = (const float*)d_in[1];
    const float* W1 = (const float*)d_in[2];
    const float* b1 = (const float*)d_in[3];
    const float* W2 = (const float*)d_in[4];
    const float* b2 = (const float*)d_in[5];

    short* S16 = (short*)d_ws;                           // 8*8192*128 shorts = 16.8 MB
    short* T1  = S16 + (size_t)L_ * B_ * D_;             // 56*32768 shorts = 3.67 MB
    short* T2  = T1 + (size_t)P_ * 2 * 32768;            // 3.67 MB  (total 24.1 MB)

    float* OUT  = (float*)d_out;                         // updated [L,B,D]
    float* MEAS = OUT + (size_t)L_ * B_ * D_;            // measures [P,B]

    transpose_w<<<dim3(P_ * 8, 2), 256, 0, stream>>>(W1, W2, T1, T2);
    prep_s16<<<dim3(1024), 256, 0, stream>>>(S, S16);
    fused<<<dim3(64, 8), 256, 0, stream>>>(S, ES, b1, b2, S16, T1, T2, OUT);
    fill_meas<<<dim3(896), 256, 0, stream>>>(MEAS);
}

// Round 2
// 385.874 us; speedup vs baseline: 2.1341x; 2.1341x over previous
//
#include <hip/hip_runtime.h>
#include <math.h>

#define L_ 8
#define D_ 128
#define B_ 8192
#define P_ 28
#define ALPHA_ 0.1f

typedef __attribute__((ext_vector_type(8))) short bf16x8;
typedef __attribute__((ext_vector_type(4))) float f32x4;
union BF8 { int4 i; bf16x8 h; short s[8]; };

__device__ __forceinline__ short f2bf(float f) {
    unsigned u = __float_as_uint(f);
    unsigned r = (u + 0x7fffu + ((u >> 16) & 1u)) >> 16;   // RNE
    return (short)(r & 0xffffu);
}
__device__ __forceinline__ unsigned rne2(float a, float b) {
    unsigned ua = __float_as_uint(a); ua += 0x7fffu + ((ua >> 16) & 1u);
    unsigned ub = __float_as_uint(b); ub += 0x7fffu + ((ub >> 16) & 1u);
    return __builtin_amdgcn_perm(ub, ua, 0x07060302);      // {b_hi16, a_hi16} -> mem order a,b
}
__device__ __forceinline__ unsigned cvt_pk_bf16(float lo, float hi) {
    unsigned r;
    asm("v_cvt_pk_bf16_f32 %0, %1, %2" : "=v"(r) : "v"(lo), "v"(hi));
    return r;
}
__device__ __forceinline__ float fast_tanh(float x) {
    float e = exp2f(x * 2.885390081777927f);               // e^{2x}
    return 1.f - 2.f * __builtin_amdgcn_rcpf(e + 1.f);
}

typedef const unsigned int __attribute__((address_space(1)))* gas_t;
typedef unsigned int __attribute__((address_space(3)))* las_t;

// ---------------------------------------------------------------------------
// W transpose -> bf16, fragment-blocked AND pre-swizzled so that a LINEAR
// global_load_lds of one 8KB kb-slice lands in LDS with the XOR-swizzle
// byte ^= ((row&7)<<4) already applied (row = output-neuron index within a
// 16-wide ct tile). Slice layout (bytes): ct*1024 + mrow*64 + kk*2, XORed.
// ---------------------------------------------------------------------------
__global__ void transpose_w(const float* __restrict__ W1, const float* __restrict__ W2,
                            short* __restrict__ T1, short* __restrict__ T2) {
    const float* W = blockIdx.y ? W2 : W1;
    short* T = blockIdx.y ? T2 : T1;
    const int p = blockIdx.x >> 3, kb = blockIdx.x & 7;
    __shared__ float tile[32][260];
    const int tid = threadIdx.x;
    for (int s = tid; s < 8192; s += 256) {
        int kk = s >> 8, n = s & 255;
        tile[kk][n] = W[((size_t)p * 256 + kb * 32 + kk) * 256 + n];
    }
    __syncthreads();
    const int n = tid;
    const int ch = n >> 7, ct = (n >> 4) & 7, mm = n & 15;
    const size_t sb = (((size_t)p * 2 + ch) * 64 + kb * 8) * 512;   // kb-slice base (shorts)
    short tmp[32];
#pragma unroll
    for (int kk = 0; kk < 32; ++kk) tmp[kk] = f2bf(tile[kk][n]);
#pragma unroll
    for (int c4 = 0; c4 < 4; ++c4) {
        BF8 u;
#pragma unroll
        for (int e = 0; e < 8; ++e) u.s[e] = tmp[c4 * 8 + e];
        const int byt = (ct * 1024 + mm * 64 + c4 * 16) ^ ((mm & 7) << 4);
        *(int4*)&T[sb + (byt >> 1)] = u.i;
    }
}

// ---------------------------------------------------------------------------
// S (f32) -> bf16 B-fragment layout, computed ONCE. Per 16-row group rg:
// 2048 shorts, elem(row,k) at (k/8 *16 + row%16)*8 + k%8.
// ---------------------------------------------------------------------------
__global__ void prep_s16(const float* __restrict__ S, short* __restrict__ S16) {
    __shared__ __align__(16) short ls[8192];            // 16 KB bounce, bank-swizzled
    const int t = threadIdx.x;
    const size_t base = (size_t)blockIdx.x * 8192;      // 64 rows x 128
#pragma unroll
    for (int rr = 0; rr < 8; ++rr) {
        const int idx = rr * 1024 + t * 4;
        const float4 v = *(const float4*)&S[base + idx];
        const int row = idx >> 7, col = idx & 127;
        const int rgl = row >> 4, mr = row & 15, kq = col >> 3, c4 = (col >> 2) & 1;
        const unsigned w0 = rne2(v.x, v.y), w1 = rne2(v.z, v.w);
        const int byt = (rgl * 4096 + kq * 256 + mr * 16 + c4 * 8) ^ ((kq & 7) << 4);
        *(uint2*)((char*)ls + byt) = (uint2){w0, w1};
    }
    __syncthreads();
#pragma unroll
    for (int r = 0; r < 4; ++r) {
        const int un = r * 256 + t;                      // 16-B unit
        const int kq = (un >> 4) & 15;
        const int byt = (un * 16) ^ ((kq & 7) << 4);
        *(int4*)&S16[base + (size_t)un * 8] = *(const int4*)((const char*)ls + byt);
    }
}

// stage source for flat stage index s (24 stages of 8KB per partner-iter):
//   0-7  : W1[p*2+0][kb 0..7]      (G1 half hh=0)
//   8-11 : W2[p*2+side][kc 0..3]   (G2 partial, K-chunks of hh=0)
//   12-19: W1[p*2+1][kb 0..7]      (G1 half hh=1)
//   20-23: W2[p*2+side][kc 4..7]
__device__ __forceinline__ const short* stage_src(int s, int k,
                                                  const short* T1, const short* T2) {
    const int it = s / 24, sub = s - it * 24;
    const int mm = it + (it >= k ? 1 : 0);
    const int i = k < mm ? k : mm;
    const int j = k < mm ? mm : k;
    const int p = i * 7 - ((i * (i - 1)) >> 1) + (j - i - 1);
    const int side = (k == i) ? 0 : 1;
    if (sub < 8)  return T1 + ((size_t)(p * 2) << 15)        + ((size_t)sub << 12);
    if (sub < 12) return T2 + ((size_t)(p * 2 + side) << 15) + ((size_t)(sub - 8) << 12);
    if (sub < 20) return T1 + ((size_t)(p * 2 + 1) << 15)    + ((size_t)(sub - 12) << 12);
    return T2 + ((size_t)(p * 2 + side) << 15) + ((size_t)(sub - 16) << 12);
}

__device__ __forceinline__ void stage_step(int s, int k, const short* T1, const short* T2,
                                           short (*Wl)[4096], int w, int lane) {
    if (s >= 168) return;
    const short* src = stage_src(s, k, T1, T2);
    short* dst = Wl[s & 1];
#pragma unroll
    for (int r = 0; r < 2; ++r) {
        const int u0 = r * 256 + w * 64;
        __builtin_amdgcn_global_load_lds((gas_t)(const void*)(src + (size_t)(u0 + lane) * 8),
                                         (las_t)(void*)(dst + u0 * 8), 16, 0, 0);
    }
}

// ---------------------------------------------------------------------------
// Fused per-layer kernel. Block = (layer k, 64 rows)  [was 128 rows: the
// 128-row version spilled ~30 VGPRs -> 900 MB scratch traffic, 776 us].
// Named register pools now: u[2][4]=32, acc1[2][4]=32, acc2[2][4]=32.
// For each of k's 7 partners in global pair order: G1 full (A=W1^T frag,
// B=S frag -> C[row=hidden, col=batch]), tanh -> bf16 H in LDS (swizzled),
// G2 restricted to layer k's 128 output cols, u += alpha*(st*(bell+b2)-u).
// ---------------------------------------------------------------------------
__launch_bounds__(256, 2)
__global__ void fused(const float* __restrict__ S, const float* __restrict__ ES,
                      const float* __restrict__ b1, const float* __restrict__ b2,
                      const short* __restrict__ S16, const short* __restrict__ T1,
                      const short* __restrict__ T2, float* __restrict__ OUT) {
    __shared__ __align__(16) short Wl[2][4096];   // 2 x 8 KB W staging (dbuf)
    __shared__ __align__(16) short Hs[8192];      // 16 KB: h half-tile [row 64][hid 128]
    const int k = blockIdx.y, rb = blockIdx.x;
    const int tid = threadIdx.x, lane = tid & 63, w = tid >> 6;
    const int m = lane & 15, q = lane >> 4;
    const int swzm = (m & 7) << 4;

    // u init: wave w owns d-slice [w*32, w*32+32), 64 rows
    const size_t srow = (size_t)k * B_ + rb * 64;
    f32x4 u[2][4];
#pragma unroll
    for (int at = 0; at < 2; ++at)
#pragma unroll
        for (int nt = 0; nt < 4; ++nt)
            u[at][nt] = *(const f32x4*)&S[(srow + nt * 16 + m) * D_ + w * 32 + at * 16 + q * 4];

    stage_step(0, k, T1, T2, Wl, w, lane);
    __syncthreads();                               // stage 0 resident

    for (int it = 0; it < 7; ++it) {
        const int mp = it + (it >= k ? 1 : 0);     // partner (ascending = global pair order)
        const int li = k < mp ? k : mp;
        const int lj = k < mp ? mp : k;
        const int p  = li * 7 - ((li * (li - 1)) >> 1) + (lj - li - 1);
        const int side = (k == li) ? 0 : 1;
        const float es = ES[li * L_ + lj];
        const float st = 1.f / (1.f + expf(-es));

        f32x4 acc2[2][4];
#pragma unroll
        for (int at = 0; at < 2; ++at)
#pragma unroll
            for (int nt = 0; nt < 4; ++nt) acc2[at][nt] = (f32x4){0.f, 0.f, 0.f, 0.f};

        for (int hh = 0; hh < 2; ++hh) {
            const int sb = it * 24 + hh * 12;
            // ---- G1: hidden half hh, wave owns 32 hidden (ct = w*2+at) ----
            f32x4 acc1[2][4];
#pragma unroll
            for (int at = 0; at < 2; ++at) {
                const f32x4 bv = *(const f32x4*)&b1[p * 256 + hh * 128 + w * 32 + at * 16 + q * 4];
#pragma unroll
                for (int nt = 0; nt < 4; ++nt) acc1[at][nt] = bv;
            }
#pragma unroll
            for (int kb = 0; kb < 8; ++kb) {
                const int s = sb + kb;
                stage_step(s + 1, k, T1, T2, Wl, w, lane);
                const int lb = (kb < 4) ? li : lj;          // comb = [s_i | s_j]
                const int kbl = kb & 3;
                const char* wb = (const char*)Wl[s & 1];
                const bf16x8 A0 = *(const bf16x8*)(wb + (((w * 2 + 0) * 1024 + m * 64 + q * 16) ^ swzm));
                const bf16x8 A1 = *(const bf16x8*)(wb + (((w * 2 + 1) * 1024 + m * 64 + q * 16) ^ swzm));
                const short* sp = S16 + ((size_t)lb * 512 + rb * 4) * 2048
                                      + ((kbl * 4 + q) * 16 + m) * 8;
#pragma unroll
                for (int nt = 0; nt < 4; ++nt) {
                    const bf16x8 Bf = *(const bf16x8*)(sp + nt * 2048);
                    acc1[0][nt] = __builtin_amdgcn_mfma_f32_16x16x32_bf16(A0, Bf, acc1[0][nt], 0, 0, 0);
                    acc1[1][nt] = __builtin_amdgcn_mfma_f32_16x16x32_bf16(A1, Bf, acc1[1][nt], 0, 0, 0);
                }
                __syncthreads();
            }
            // ---- tanh -> bf16 -> swizzled LDS H (per lane: 4 consecutive hidden, 1 row) ----
#pragma unroll
            for (int at = 0; at < 2; ++at)
#pragma unroll
                for (int nt = 0; nt < 4; ++nt) {
                    const float v0 = fast_tanh(acc1[at][nt][0]);
                    const float v1 = fast_tanh(acc1[at][nt][1]);
                    const float v2 = fast_tanh(acc1[at][nt][2]);
                    const float v3 = fast_tanh(acc1[at][nt][3]);
                    const unsigned p0 = cvt_pk_bf16(v0, v1);
                    const unsigned p1 = cvt_pk_bf16(v2, v3);
                    const int row = nt * 16 + m;
                    const int hb = (w * 32 + at * 16 + q * 4) * 2;
                    *(uint2*)((char*)Hs + ((row * 256 + hb) ^ swzm)) = (uint2){p0, p1};
                }
            __syncthreads();                       // H half visible to all waves
            // ---- G2 partial: K-chunks of this hidden half, output = side's 128 cols ----
#pragma unroll
            for (int kc = 0; kc < 4; ++kc) {
                const int s = sb + 8 + kc;
                stage_step(s + 1, k, T1, T2, Wl, w, lane);
                const char* wb = (const char*)Wl[s & 1];
                const bf16x8 A0 = *(const bf16x8*)(wb + (((w * 2 + 0) * 1024 + m * 64 + q * 16) ^ swzm));
                const bf16x8 A1 = *(const bf16x8*)(wb + (((w * 2 + 1) * 1024 + m * 64 + q * 16) ^ swzm));
                const int cb = kc * 64 + q * 16;
#pragma unroll
                for (int nt = 0; nt < 4; ++nt) {
                    const int row = nt * 16 + m;
                    const bf16x8 Hf = *(const bf16x8*)((const char*)Hs + ((row * 256 + cb) ^ swzm));
                    acc2[0][nt] = __builtin_amdgcn_mfma_f32_16x16x32_bf16(A0, Hf, acc2[0][nt], 0, 0, 0);
                    acc2[1][nt] = __builtin_amdgcn_mfma_f32_16x16x32_bf16(A1, Hf, acc2[1][nt], 0, 0, 0);
                }
                __syncthreads();
            }
        }
        // ---- sequential propagation step (exact reference order, f32) ----
#pragma unroll
        for (int at = 0; at < 2; ++at) {
            const f32x4 bv = *(const f32x4*)&b2[p * 256 + side * 128 + w * 32 + at * 16 + q * 4];
#pragma unroll
            for (int nt = 0; nt < 4; ++nt)
#pragma unroll
                for (int r = 0; r < 4; ++r) {
                    const float e = st * (acc2[at][nt][r] + bv[r]);
                    u[at][nt][r] += ALPHA_ * (e - u[at][nt][r]);
                }
        }
    }

#pragma unroll
    for (int nt = 0; nt < 4; ++nt)
#pragma unroll
        for (int at = 0; at < 2; ++at)
            *(f32x4*)&OUT[(srow + nt * 16 + m) * D_ + w * 32 + at * 16 + q * 4] = u[at][nt];
}

// measures analytically constant (lam1 == 1 after normalize):
// (127+127-255)*1e-12*(-ln 1e-12) = -2.7631021115928547e-11
__global__ void fill_meas(float* __restrict__ M) {
    int t = blockIdx.x * 256 + threadIdx.x;
    if (t < P_ * B_) M[t] = -2.7631021115928547e-11f;
}

extern "C" void kernel_launch(void* const* d_in, const int* in_sizes, int n_in,
                              void* d_out, int out_size, void* d_ws, size_t ws_size,
                              hipStream_t stream) {
    const float* S  = (const float*)d_in[0];
    const float* ES = (const float*)d_in[1];
    const float* W1 = (const float*)d_in[2];
    const float* b1 = (const float*)d_in[3];
    const float* W2 = (const float*)d_in[4];
    const float* b2 = (const float*)d_in[5];

    short* S16 = (short*)d_ws;                           // 8*8192*128 shorts = 16.8 MB
    short* T1  = S16 + (size_t)L_ * B_ * D_;             // 56*32768 shorts = 3.67 MB
    short* T2  = T1 + (size_t)P_ * 2 * 32768;            // 3.67 MB  (total 24.1 MB)

    float* OUT  = (float*)d_out;                         // updated [L,B,D]
    float* MEAS = OUT + (size_t)L_ * B_ * D_;            // measures [P,B]

    transpose_w<<<dim3(P_ * 8, 2), 256, 0, stream>>>(W1, W2, T1, T2);
    prep_s16<<<dim3(1024), 256, 0, stream>>>(S, S16);
    fused<<<dim3(128, 8), 256, 0, stream>>>(S, ES, b1, b2, S16, T1, T2, OUT);
    fill_meas<<<dim3(896), 256, 0, stream>>>(MEAS);
}

// Round 3
// 306.905 us; speedup vs baseline: 2.6832x; 1.2573x over previous
//
#include <hip/hip_runtime.h>
#include <math.h>

#define L_ 8
#define D_ 128
#define B_ 8192
#define P_ 28
#define ALPHA_ 0.1f

typedef __attribute__((ext_vector_type(8))) short bf16x8;
typedef __attribute__((ext_vector_type(4))) float f32x4;
union BF8 { int4 i; bf16x8 h; short s[8]; };

__device__ __forceinline__ short f2bf(float f) {
    unsigned u = __float_as_uint(f);
    unsigned r = (u + 0x7fffu + ((u >> 16) & 1u)) >> 16;   // RNE
    return (short)(r & 0xffffu);
}
__device__ __forceinline__ unsigned rne2(float a, float b) {
    unsigned ua = __float_as_uint(a); ua += 0x7fffu + ((ua >> 16) & 1u);
    unsigned ub = __float_as_uint(b); ub += 0x7fffu + ((ub >> 16) & 1u);
    return __builtin_amdgcn_perm(ub, ua, 0x07060302);      // {b_hi16, a_hi16} -> mem order a,b
}
__device__ __forceinline__ unsigned cvt_pk_bf16(float lo, float hi) {
    unsigned r;
    asm("v_cvt_pk_bf16_f32 %0, %1, %2" : "=v"(r) : "v"(lo), "v"(hi));
    return r;
}
__device__ __forceinline__ float fast_tanh(float x) {
    float e = exp2f(x * 2.885390081777927f);               // e^{2x}
    return 1.f - 2.f * __builtin_amdgcn_rcpf(e + 1.f);
}

typedef const unsigned int __attribute__((address_space(1)))* gas_t;
typedef unsigned int __attribute__((address_space(3)))* las_t;

// ---------------------------------------------------------------------------
// W transpose -> bf16, fragment-blocked AND pre-swizzled so that a LINEAR
// global_load_lds of one 8KB kb-slice lands in LDS with the XOR-swizzle
// byte ^= ((row&7)<<4) already applied (row = output-neuron index within a
// 16-wide ct tile). Slice layout (bytes): ct*1024 + mrow*64 + kk*2, XORed.
// ---------------------------------------------------------------------------
__global__ void transpose_w(const float* __restrict__ W1, const float* __restrict__ W2,
                            short* __restrict__ T1, short* __restrict__ T2) {
    const float* W = blockIdx.y ? W2 : W1;
    short* T = blockIdx.y ? T2 : T1;
    const int p = blockIdx.x >> 3, kb = blockIdx.x & 7;
    __shared__ float tile[32][260];
    const int tid = threadIdx.x;
    for (int s = tid; s < 8192; s += 256) {
        int kk = s >> 8, n = s & 255;
        tile[kk][n] = W[((size_t)p * 256 + kb * 32 + kk) * 256 + n];
    }
    __syncthreads();
    const int n = tid;
    const int ch = n >> 7, ct = (n >> 4) & 7, mm = n & 15;
    const size_t sb = (((size_t)p * 2 + ch) * 64 + kb * 8) * 512;   // kb-slice base (shorts)
    short tmp[32];
#pragma unroll
    for (int kk = 0; kk < 32; ++kk) tmp[kk] = f2bf(tile[kk][n]);
#pragma unroll
    for (int c4 = 0; c4 < 4; ++c4) {
        BF8 u;
#pragma unroll
        for (int e = 0; e < 8; ++e) u.s[e] = tmp[c4 * 8 + e];
        const int byt = (ct * 1024 + mm * 64 + c4 * 16) ^ ((mm & 7) << 4);
        *(int4*)&T[sb + (byt >> 1)] = u.i;
    }
}

// ---------------------------------------------------------------------------
// S (f32) -> bf16 B-fragment layout, computed ONCE. Per 16-row group rg:
// 2048 shorts, elem(row,k) at (k/8 *16 + row%16)*8 + k%8.
// ---------------------------------------------------------------------------
__global__ void prep_s16(const float* __restrict__ S, short* __restrict__ S16) {
    __shared__ __align__(16) short ls[8192];            // 16 KB bounce, bank-swizzled
    const int t = threadIdx.x;
    const size_t base = (size_t)blockIdx.x * 8192;      // 64 rows x 128
#pragma unroll
    for (int rr = 0; rr < 8; ++rr) {
        const int idx = rr * 1024 + t * 4;
        const float4 v = *(const float4*)&S[base + idx];
        const int row = idx >> 7, col = idx & 127;
        const int rgl = row >> 4, mr = row & 15, kq = col >> 3, c4 = (col >> 2) & 1;
        const unsigned w0 = rne2(v.x, v.y), w1 = rne2(v.z, v.w);
        const int byt = (rgl * 4096 + kq * 256 + mr * 16 + c4 * 8) ^ ((kq & 7) << 4);
        *(uint2*)((char*)ls + byt) = (uint2){w0, w1};
    }
    __syncthreads();
#pragma unroll
    for (int r = 0; r < 4; ++r) {
        const int un = r * 256 + t;                      // 16-B unit
        const int kq = (un >> 4) & 15;
        const int byt = (un * 16) ^ ((kq & 7) << 4);
        *(int4*)&S16[base + (size_t)un * 8] = *(const int4*)((const char*)ls + byt);
    }
}

// Stage order within a partner-iter (24 x 8KB slices, parity = sub&1 since 24 even):
//   sub 0-7  : W1[p*2+0][kb]   (G1 hidden-half 0)
//   sub 8-15 : W1[p*2+1][kb]   (G1 hidden-half 1)
//   sub 16-23: W2[p*2+side][kb] (G2, full K)
__device__ __forceinline__ void stage_issue(int it, int sub, int k,
                                            const short* T1, const short* T2,
                                            short (*Wl)[4096], int w, int lane) {
    if (it >= 7) return;
    const int mm = it + (it >= k ? 1 : 0);
    const int i = k < mm ? k : mm;
    const int j = k < mm ? mm : k;
    const int p = i * 7 - ((i * (i - 1)) >> 1) + (j - i - 1);
    const int side = (k == i) ? 0 : 1;
    const short* src;
    if (sub < 8)       src = T1 + ((size_t)(p * 2) << 15)        + ((size_t)sub << 12);
    else if (sub < 16) src = T1 + ((size_t)(p * 2 + 1) << 15)    + ((size_t)(sub - 8) << 12);
    else               src = T2 + ((size_t)(p * 2 + side) << 15) + ((size_t)(sub - 16) << 12);
    short* dst = Wl[sub & 1];
#pragma unroll
    for (int r = 0; r < 2; ++r) {
        const int u0 = r * 256 + w * 64;
        __builtin_amdgcn_global_load_lds((gas_t)(const void*)(src + (size_t)(u0 + lane) * 8),
                                         (las_t)(void*)(dst + u0 * 8), 16, 0, 0);
    }
}

// ---------------------------------------------------------------------------
// Fused per-layer kernel, block = (layer k, 64 rows).
// KEY CHANGE vs round 2: full H (64 x 256) kept in LDS so acc1 (G1) and
// acc2 (G2) liveness never overlap -> peak regs ~95 (was ~140, spilled
// ~400 MB scratch = the whole 298 us). Hs uses the S16 fragment layout:
// both tanh-store and G2 B-frag reads are exactly bank-conflict-free.
// ---------------------------------------------------------------------------
__launch_bounds__(256, 3)
__global__ void fused(const float* __restrict__ S, const float* __restrict__ ES,
                      const float* __restrict__ b1, const float* __restrict__ b2,
                      const short* __restrict__ S16, const short* __restrict__ T1,
                      const short* __restrict__ T2, float* __restrict__ OUT) {
    __shared__ __align__(16) short Wl[2][4096];   // 2 x 8 KB W staging (dbuf)
    __shared__ __align__(16) short Hs[16384];     // 32 KB: full h tile, fragment layout
    const int k = blockIdx.y, rb = blockIdx.x;
    const int tid = threadIdx.x, lane = tid & 63, w = tid >> 6;
    const int m = lane & 15, q = lane >> 4;
    const int swzm = (m & 7) << 4;
    char* const hsb = (char*)Hs;

    // u init: wave w owns d-slice [w*32, w*32+32), 64 rows
    const size_t srow = (size_t)k * B_ + rb * 64;
    f32x4 u[2][4];
#pragma unroll
    for (int at = 0; at < 2; ++at)
#pragma unroll
        for (int nt = 0; nt < 4; ++nt)
            u[at][nt] = *(const f32x4*)&S[(srow + nt * 16 + m) * D_ + w * 32 + at * 16 + q * 4];

    stage_issue(0, 0, k, T1, T2, Wl, w, lane);
    __syncthreads();                               // stage 0 resident

    for (int it = 0; it < 7; ++it) {
        const int mp = it + (it >= k ? 1 : 0);     // partner (ascending = global pair order)
        const int li = k < mp ? k : mp;
        const int lj = k < mp ? mp : k;
        const int p  = li * 7 - ((li * (li - 1)) >> 1) + (lj - li - 1);
        const int side = (k == li) ? 0 : 1;
        const float es = ES[li * L_ + lj];
        const float st = 1.f / (1.f + expf(-es));

        // ================= G1: both hidden halves -> full H in LDS =========
        for (int hh = 0; hh < 2; ++hh) {
            f32x4 acc1[2][4];
#pragma unroll
            for (int at = 0; at < 2; ++at) {
                const f32x4 bv = *(const f32x4*)&b1[p * 256 + hh * 128 + w * 32 + at * 16 + q * 4];
#pragma unroll
                for (int nt = 0; nt < 4; ++nt) acc1[at][nt] = bv;
            }
#pragma unroll
            for (int kb = 0; kb < 8; ++kb) {
                const int d = hh * 8 + kb;
                if (d < 23) stage_issue(it, d + 1, k, T1, T2, Wl, w, lane);
                else        stage_issue(it + 1, 0, k, T1, T2, Wl, w, lane);
                const int lb = (kb < 4) ? li : lj;          // comb = [s_i | s_j]
                const int kbl = kb & 3;
                const char* wb = (const char*)Wl[d & 1];
                const bf16x8 A0 = *(const bf16x8*)(wb + (((w * 2 + 0) * 1024 + m * 64 + q * 16) ^ swzm));
                const bf16x8 A1 = *(const bf16x8*)(wb + (((w * 2 + 1) * 1024 + m * 64 + q * 16) ^ swzm));
                const short* sp = S16 + ((size_t)lb * 512 + rb * 4) * 2048
                                      + ((kbl * 4 + q) * 16 + m) * 8;
#pragma unroll
                for (int nt = 0; nt < 4; ++nt) {
                    const bf16x8 Bf = *(const bf16x8*)(sp + nt * 2048);
                    acc1[0][nt] = __builtin_amdgcn_mfma_f32_16x16x32_bf16(A0, Bf, acc1[0][nt], 0, 0, 0);
                    acc1[1][nt] = __builtin_amdgcn_mfma_f32_16x16x32_bf16(A1, Bf, acc1[1][nt], 0, 0, 0);
                }
                __syncthreads();
            }
            // tanh -> bf16 -> Hs in FRAGMENT layout (conflict-free 8B stores):
            // hidden = hh*128 + (w*2+at)*16 + q*4 + rr, row = nt*16+m
            // byte = nt*8192 + (hidden/8)*256 + m*16 + (q&1)*8
#pragma unroll
            for (int at = 0; at < 2; ++at) {
                const int cb = (hh * 16 + w * 4 + at * 2 + (q >> 1)) * 256 + m * 16 + (q & 1) * 8;
#pragma unroll
                for (int nt = 0; nt < 4; ++nt) {
                    const float v0 = fast_tanh(acc1[at][nt][0]);
                    const float v1 = fast_tanh(acc1[at][nt][1]);
                    const float v2 = fast_tanh(acc1[at][nt][2]);
                    const float v3 = fast_tanh(acc1[at][nt][3]);
                    const unsigned p0 = cvt_pk_bf16(v0, v1);
                    const unsigned p1 = cvt_pk_bf16(v2, v3);
                    *(uint2*)(hsb + nt * 8192 + cb) = (uint2){p0, p1};
                }
            }
        }
        __syncthreads();                           // full H visible to all waves

        // ================= G2 over full K=256, output = side's 128 cols ====
        f32x4 acc2[2][4];
#pragma unroll
        for (int at = 0; at < 2; ++at)
#pragma unroll
            for (int nt = 0; nt < 4; ++nt) acc2[at][nt] = (f32x4){0.f, 0.f, 0.f, 0.f};

#pragma unroll
        for (int kb = 0; kb < 8; ++kb) {
            const int d = 16 + kb;
            if (d < 23) stage_issue(it, d + 1, k, T1, T2, Wl, w, lane);
            else        stage_issue(it + 1, 0, k, T1, T2, Wl, w, lane);
            const char* wb = (const char*)Wl[d & 1];
            const bf16x8 A0 = *(const bf16x8*)(wb + (((w * 2 + 0) * 1024 + m * 64 + q * 16) ^ swzm));
            const bf16x8 A1 = *(const bf16x8*)(wb + (((w * 2 + 1) * 1024 + m * 64 + q * 16) ^ swzm));
            const int hc = (kb * 4 + q) * 256 + m * 16;      // fragment-layout read
#pragma unroll
            for (int nt = 0; nt < 4; ++nt) {
                const bf16x8 Hf = *(const bf16x8*)(hsb + nt * 8192 + hc);
                acc2[0][nt] = __builtin_amdgcn_mfma_f32_16x16x32_bf16(A0, Hf, acc2[0][nt], 0, 0, 0);
                acc2[1][nt] = __builtin_amdgcn_mfma_f32_16x16x32_bf16(A1, Hf, acc2[1][nt], 0, 0, 0);
            }
            __syncthreads();
        }

        // ---- sequential propagation step (exact reference order, f32) ----
#pragma unroll
        for (int at = 0; at < 2; ++at) {
            const f32x4 bv = *(const f32x4*)&b2[p * 256 + side * 128 + w * 32 + at * 16 + q * 4];
#pragma unroll
            for (int nt = 0; nt < 4; ++nt)
#pragma unroll
                for (int r = 0; r < 4; ++r) {
                    const float e = st * (acc2[at][nt][r] + bv[r]);
                    u[at][nt][r] += ALPHA_ * (e - u[at][nt][r]);
                }
        }
    }

#pragma unroll
    for (int nt = 0; nt < 4; ++nt)
#pragma unroll
        for (int at = 0; at < 2; ++at)
            *(f32x4*)&OUT[(srow + nt * 16 + m) * D_ + w * 32 + at * 16 + q * 4] = u[at][nt];
}

// measures analytically constant (lam1 == 1 after normalize):
// (127+127-255)*1e-12*(-ln 1e-12) = -2.7631021115928547e-11
__global__ void fill_meas(float* __restrict__ M) {
    int t = blockIdx.x * 256 + threadIdx.x;
    if (t < P_ * B_) M[t] = -2.7631021115928547e-11f;
}

extern "C" void kernel_launch(void* const* d_in, const int* in_sizes, int n_in,
                              void* d_out, int out_size, void* d_ws, size_t ws_size,
                              hipStream_t stream) {
    const float* S  = (const float*)d_in[0];
    const float* ES = (const float*)d_in[1];
    const float* W1 = (const float*)d_in[2];
    const float* b1 = (const float*)d_in[3];
    const float* W2 = (const float*)d_in[4];
    const float* b2 = (const float*)d_in[5];

    short* S16 = (short*)d_ws;                           // 8*8192*128 shorts = 16.8 MB
    short* T1  = S16 + (size_t)L_ * B_ * D_;             // 56*32768 shorts = 3.67 MB
    short* T2  = T1 + (size_t)P_ * 2 * 32768;            // 3.67 MB  (total 24.1 MB)

    float* OUT  = (float*)d_out;                         // updated [L,B,D]
    float* MEAS = OUT + (size_t)L_ * B_ * D_;            // measures [P,B]

    transpose_w<<<dim3(P_ * 8, 2), 256, 0, stream>>>(W1, W2, T1, T2);
    prep_s16<<<dim3(1024), 256, 0, stream>>>(S, S16);
    fused<<<dim3(128, 8), 256, 0, stream>>>(S, ES, b1, b2, S16, T1, T2, OUT);
    fill_meas<<<dim3(896), 256, 0, stream>>>(MEAS);
}